// Round 7
// baseline (312.217 us; speedup 1.0000x reference)
//
#include <hip/hip_runtime.h>
#include <hip/hip_bf16.h>
#include <math.h>

// ---------------------------------------------------------------------------
// GCN 2-layer. A_hat = D^-1/2 (A+I) D^-1/2 factored: scale GEMM rows by dinv
// (epilogue), gather-sum neighbors, scale by dinv[dst], add self term.
// R8: CSR build, zero per-edge global atomics (two-level counting sort).
// R10: gemm1 whole-Bt-in-LDS + pre-swizzled B image. R11: 2 row-tiles/wave.
// R12-R14: gather kernels pushed down the issue-depth gradient (quarter-wave
// 16B, feature-split two-pass, unroll-4; partA single-read paired loads,
// partB 512t).
// R15 (this): agg1 FULL-CHUNK issue -- all <=8 octet loads of a 64-edge
// chunk issued into a P[8] register ring before any accumulate (128B
// outstanding/lane, 2x R14 depth); both feature passes in ONE dispatch
// (grid 2x, fofs by block half; pass-0 blocks dispatch first so the L2
// working-set split survives). agg2 same treatment (uint2 P[8]).
// Top-5 counters stay occluded by the harness 409.6MB re-poison (~60us).
// ---------------------------------------------------------------------------

#define FEAT1 512
#define FEAT2 128
#define FEAT3 40

typedef __attribute__((ext_vector_type(8))) short bf16x8;
typedef __attribute__((ext_vector_type(4))) float f32x4;

struct __align__(16) ll2 { long long x, y; };

__device__ __forceinline__ unsigned short f2bf(float f) {
    union { float f; unsigned u; } c; c.f = f;
    unsigned r = c.u + 0x7fff + ((c.u >> 16) & 1);   // round-nearest-even
    return (unsigned short)(r >> 16);
}
__device__ __forceinline__ float bf2f(unsigned v16) {
    union { unsigned u; float f; } c; c.u = v16 << 16;
    return c.f;
}

// f32x4 pair -> 8 bf16 via v_cvt_pk_bf16_f32 (compiler emits pk from casts)
__device__ __forceinline__ bf16x8 pack_bf8(f32x4 a, f32x4 b) {
    union { __hip_bfloat162 h[4]; bf16x8 v; } u;
    u.h[0] = __float22bfloat162_rn(make_float2(a[0], a[1]));
    u.h[1] = __float22bfloat162_rn(make_float2(a[2], a[3]));
    u.h[2] = __float22bfloat162_rn(make_float2(b[0], b[1]));
    u.h[3] = __float22bfloat162_rn(make_float2(b[2], b[3]));
    return u.v;
}

// ---- partA: bucket edges by dst>>8; LDS hist; 1 global claim/bucket/block --
// Single read of the edge list, 2 edges per thread per round via 16B/8B
// paired loads; edges held in registers between hist pass and scatter pass.
__launch_bounds__(1024)
__global__ void partA_kernel(const int* __restrict__ ei,
                             int* __restrict__ gbkt, unsigned* __restrict__ part,
                             int bktCap, long E, int NB) {
    __shared__ int hist[256], lbase[256], lcur[256];
    __shared__ int anyv;
    int t = threadIdx.x;
    if (t == 0) anyv = 0;
    if (t < 256) { hist[t] = 0; lcur[t] = 0; }
    __syncthreads();
    if (t < 256 && ei[2 * t + 1] != 0) anyv = 1;   // benign race
    __syncthreads();
    int f64 = (anyv == 0) ? 1 : 0;
    const long long* ei64 = (const long long*)ei;

    long chunk = (E + gridDim.x - 1) / gridDim.x;   // 6250 <= 4*2048
    long start = (long)blockIdx.x * chunk;
    long end = start + chunk; if (end > E) end = E;

    int srcs[8], dsts[8];
    #pragma unroll
    for (int r = 0; r < 4; r++) {
        long e0 = start + (long)r * 2048 + 2 * t;   // start even, e0 even
        if (e0 + 1 < end) {
            if (f64) {
                ll2 s2 = *(const ll2*)(ei64 + e0);
                ll2 d2 = *(const ll2*)(ei64 + E + e0);
                srcs[2 * r] = (int)s2.x; srcs[2 * r + 1] = (int)s2.y;
                dsts[2 * r] = (int)d2.x; dsts[2 * r + 1] = (int)d2.y;
            } else {
                int2 s2 = *(const int2*)(ei + e0);
                int2 d2 = *(const int2*)(ei + E + e0);
                srcs[2 * r] = s2.x; srcs[2 * r + 1] = s2.y;
                dsts[2 * r] = d2.x; dsts[2 * r + 1] = d2.y;
            }
            atomicAdd(&hist[dsts[2 * r] >> 8], 1);
            atomicAdd(&hist[dsts[2 * r + 1] >> 8], 1);
        } else if (e0 < end) {
            if (f64) { srcs[2 * r] = (int)ei64[e0]; dsts[2 * r] = (int)ei64[E + e0]; }
            else     { srcs[2 * r] = ei[e0];        dsts[2 * r] = ei[E + e0]; }
            atomicAdd(&hist[dsts[2 * r] >> 8], 1);
        }
    }
    __syncthreads();
    if (t < NB && hist[t]) lbase[t] = atomicAdd(&gbkt[t], hist[t]);
    __syncthreads();

    #pragma unroll
    for (int r = 0; r < 4; r++) {
        long e0 = start + (long)r * 2048 + 2 * t;
        #pragma unroll
        for (int u = 0; u < 2; u++) {
            if (e0 + u < end) {
                int bkt = dsts[2 * r + u] >> 8;
                int pos = lbase[bkt] + atomicAdd(&lcur[bkt], 1);
                if (pos < bktCap)
                    part[(long)bkt * bktCap + pos] =
                        (unsigned)srcs[2 * r + u] | ((unsigned)(dsts[2 * r + u] & 255) << 17);
            }
        }
    }
}

// ---- partB: bucket-base scan + per-bucket degree hist/scan -> offsets/dinv;
//      LDS-cursor scatter -> col. 512 threads (scans guarded to t<256). ----
__launch_bounds__(512)
__global__ void partB_kernel(const unsigned* __restrict__ part, int bktCap,
                             const int* __restrict__ gbkt,
                             int* __restrict__ offsets, float* __restrict__ dinv,
                             int* __restrict__ col, int N, int E) {
    __shared__ int h[256], sc[256], cur[256];
    int b = blockIdx.x, t = threadIdx.x;
    int NB = gridDim.x;

    // inclusive scan of gbkt (redundant per block) -> bucket base
    if (t < 256) sc[t] = (t < NB) ? gbkt[t] : 0;
    __syncthreads();
    #pragma unroll
    for (int d = 1; d < 256; d <<= 1) {
        int tv = 0;
        if (t < 256 && t >= d) tv = sc[t - d];
        __syncthreads();
        if (t < 256) sc[t] += tv;
        __syncthreads();
    }
    int base = (b == 0) ? 0 : sc[b - 1];
    if (b == 0 && t == 0) offsets[N] = E;

    int n = gbkt[b]; if (n > bktCap) n = bktCap;
    int lo = b << 8;
    const unsigned* p = part + (long)b * bktCap;
    if (t < 256) h[t] = 0;
    __syncthreads();
    for (int i = t; i < n; i += 512) atomicAdd(&h[(p[i] >> 17) & 255], 1);
    __syncthreads();
    int cnt = (t < 256) ? h[t] : 0;
    if (t < 256) sc[t] = cnt;
    __syncthreads();
    #pragma unroll
    for (int d = 1; d < 256; d <<= 1) {
        int tv = 0;
        if (t < 256 && t >= d) tv = sc[t - d];
        __syncthreads();
        if (t < 256) sc[t] += tv;
        __syncthreads();
    }
    if (t < 256) {
        int ex = sc[t] - cnt;
        int node = lo + t;
        if (node < N) {
            offsets[node] = base + ex;
            dinv[node] = 1.0f / sqrtf((float)(cnt + 1));   // +1 self-loop
        }
        cur[t] = ex;
    }
    __syncthreads();
    for (int i = t; i < n; i += 512) {
        unsigned u = p[i];
        int r = atomicAdd(&cur[(u >> 17) & 255], 1);
        col[base + r] = u & 0x1FFFF;
    }
}

// ---- merged weight prep: W1 -> Bt (pre-swizzled), W2 -> Bt2, zero gbkt -----
__global__ void wbt_kernel(const float* __restrict__ W1, const float* __restrict__ W2,
                           unsigned short* __restrict__ Bt, unsigned short* __restrict__ Bt2,
                           int* __restrict__ gbkt) {
    int b = blockIdx.x;                 // 0..175
    if (b == 0 && threadIdx.x < 256) gbkt[threadIdx.x] = 0;
    if (b < FEAT2) {
        int r = b, x7 = r & 7;
        for (int k = threadIdx.x; k < FEAT1; k += blockDim.x) {
            int c = k >> 3, j = k & 7;
            int eo = (((c ^ x7) << 3) | j);
            Bt[(long)r * FEAT1 + eo] = f2bf(W1[(long)k * FEAT2 + r]);
        }
    } else {
        int n = b - FEAT2;              // 0..47
        for (int k = threadIdx.x; k < FEAT2; k += blockDim.x)
            Bt2[(long)n * FEAT2 + k] = (n < FEAT3) ? f2bf(W2[(long)k * FEAT3 + n]) : 0;
    }
}

// ---- GEMM1 (MFMA): [M,512]f32 x Bt[128][512]bf16(swz) -> h1s bf16, *dinv ---
#define G1_NW 8   // waves per block (512 threads); 16 row-tiles per block
__launch_bounds__(512, 2)
__global__ void gemm1_mfma_kernel(const float* __restrict__ A,
                                  const unsigned short* __restrict__ Bsw,
                                  const float* __restrict__ dinv,
                                  unsigned short* __restrict__ C, int M) {
    __shared__ unsigned short Bl[FEAT2 * FEAT1];   // 128 KB swizzled B image
    int t = threadIdx.x;

    // stage: 512 threads x 16B x 16 rounds = 128 KB, linear copy
    {
        uint4 tmp[16];
        #pragma unroll
        for (int r = 0; r < 16; r++)
            tmp[r] = *(const uint4*)((const char*)Bsw + (size_t)t * 16 + (size_t)r * 8192);
        #pragma unroll
        for (int r = 0; r < 16; r++)
            *(uint4*)((char*)Bl + (size_t)t * 16 + (size_t)r * 8192) = tmp[r];
    }
    __syncthreads();

    int w = t >> 6, lane = t & 63;
    int quad = lane >> 4, r15 = lane & 15;
    int row0 = (blockIdx.x * (G1_NW * 2) + w * 2) * 16;   // first of 2 tiles
    int x7 = r15 & 7;

    int ar0 = row0 + r15;      if (ar0 >= M) ar0 = M - 1;  // clamp (see gemm2)
    int ar1 = row0 + 16 + r15; if (ar1 >= M) ar1 = M - 1;
    const float* ap0 = A + (long)ar0 * FEAT1 + quad * 8;
    const float* ap1 = A + (long)ar1 * FEAT1 + quad * 8;

    f32x4 ra0[3][2], ra1[3][2];          // depth-3 prefetch rings
    #pragma unroll
    for (int p = 0; p < 3; p++) {
        ra0[p][0] = *(const f32x4*)(ap0 + p * 32);
        ra0[p][1] = *(const f32x4*)(ap0 + p * 32 + 4);
        ra1[p][0] = *(const f32x4*)(ap1 + p * 32);
        ra1[p][1] = *(const f32x4*)(ap1 + p * 32 + 4);
    }

    f32x4 acc0[8], acc1[8];
    #pragma unroll
    for (int nt = 0; nt < 8; nt++) {
        acc0[nt] = (f32x4){0.f, 0.f, 0.f, 0.f};
        acc1[nt] = (f32x4){0.f, 0.f, 0.f, 0.f};
    }

    #pragma unroll
    for (int ks = 0; ks < 16; ks++) {
        int sl = ks % 3;
        bf16x8 af0 = pack_bf8(ra0[sl][0], ra0[sl][1]);
        bf16x8 af1 = pack_bf8(ra1[sl][0], ra1[sl][1]);
        if (ks < 13) {                   // refill freed slot (ks+3)
            ra0[sl][0] = *(const f32x4*)(ap0 + (ks + 3) * 32);
            ra0[sl][1] = *(const f32x4*)(ap0 + (ks + 3) * 32 + 4);
            ra1[sl][0] = *(const f32x4*)(ap1 + (ks + 3) * 32);
            ra1[sl][1] = *(const f32x4*)(ap1 + (ks + 3) * 32 + 4);
        }
        #pragma unroll
        for (int nt = 0; nt < 8; nt++) {
            // swizzled chunk: (ks*4 + quad) ^ (r15&7), 16B units
            int eo = (nt * 16 + r15) * FEAT1 + (((ks * 4 + quad) ^ x7) << 3);
            bf16x8 bfrag = *(const bf16x8*)(Bl + eo);
            acc0[nt] = __builtin_amdgcn_mfma_f32_16x16x32_bf16(af0, bfrag, acc0[nt], 0, 0, 0);
            acc1[nt] = __builtin_amdgcn_mfma_f32_16x16x32_bf16(af1, bfrag, acc1[nt], 0, 0, 0);
        }
    }

    // C/D: col=lane&15, row=quad*4+reg
    #pragma unroll
    for (int tile = 0; tile < 2; tile++) {
        #pragma unroll
        for (int reg = 0; reg < 4; reg++) {
            int orow = row0 + tile * 16 + quad * 4 + reg;
            if (orow < M) {
                float di = dinv[orow];
                #pragma unroll
                for (int nt = 0; nt < 8; nt++) {
                    float v = (tile == 0) ? acc0[nt][reg] : acc1[nt][reg];
                    C[(long)orow * FEAT2 + nt * 16 + r15] = f2bf(v * di);
                }
            }
        }
    }
}

// ---- Aggregation 1: feature-split octet gathers, FULL-CHUNK issue ----------
// One dispatch covers both passes: blocks [0,nb) do feats 0..63, [nb,2nb)
// do 64..127 (pass-0 blocks dispatch first -> working-set split preserved).
// Lane l: q=l>>3 (edge slot), j=l&7 covers 8 feats (one dwordx4). All <=8
// octet loads of a 64-edge chunk are issued into P[8] before accumulating
// (chunk-uniform branches; 128B outstanding/lane).
__launch_bounds__(256)
__global__ void agg1_kernel(const unsigned short* __restrict__ h1s,
                            const int* __restrict__ col, const int* __restrict__ off,
                            const float* __restrict__ dinv, const float* __restrict__ b1,
                            unsigned short* __restrict__ a1, int N, int nb) {
    int bb = blockIdx.x;
    int fofs = 0;
    if (bb >= nb) { fofs = 64; bb -= nb; }
    int node = bb * 4 + (threadIdx.x >> 6);
    if (node >= N) return;
    int l = threadIdx.x & 63;
    int q = l >> 3, j = l & 7;
    const unsigned short* hp = h1s + fofs + 8 * j;
    int o0 = off[node], o1 = off[node + 1];
    float s0 = 0.f, s1 = 0.f, s2 = 0.f, s3 = 0.f,
          s4 = 0.f, s5 = 0.f, s6 = 0.f, s7 = 0.f;

    #define ACC8(P)                                                     \
        do {                                                            \
            s0 += __uint_as_float((P).x << 16);                         \
            s1 += __uint_as_float((P).x & 0xffff0000u);                 \
            s2 += __uint_as_float((P).y << 16);                         \
            s3 += __uint_as_float((P).y & 0xffff0000u);                 \
            s4 += __uint_as_float((P).z << 16);                         \
            s5 += __uint_as_float((P).z & 0xffff0000u);                 \
            s6 += __uint_as_float((P).w << 16);                         \
            s7 += __uint_as_float((P).w & 0xffff0000u);                 \
        } while (0)

    for (int base = o0; base < o1; base += 64) {
        int cnt = min(64, o1 - base);
        int myc = (l < cnt) ? col[base + l] : 0;
        int octs = cnt >> 3;
        // issue ALL octet loads (octs is wave-uniform -> cheap branches)
        uint4 P[8];
        #pragma unroll
        for (int i = 0; i < 8; i++) {
            if (i < octs) {
                int c = __shfl(myc, 8 * i + q);
                P[i] = *(const uint4*)(hp + (long)c * FEAT2);
            }
        }
        #pragma unroll
        for (int i = 0; i < 8; i++)
            if (i < octs) ACC8(P[i]);
        int e = (octs << 3) + q;         // tail: up to 7 edges (e <= 63)
        int ct = __shfl(myc, e);
        if (e < cnt) {
            uint4 pt = *(const uint4*)(hp + (long)ct * FEAT2);
            ACC8(pt);
        }
    }
    #undef ACC8

    // combine the 8 edge slots
    s0 += __shfl_xor(s0, 8);  s1 += __shfl_xor(s1, 8);
    s2 += __shfl_xor(s2, 8);  s3 += __shfl_xor(s3, 8);
    s4 += __shfl_xor(s4, 8);  s5 += __shfl_xor(s5, 8);
    s6 += __shfl_xor(s6, 8);  s7 += __shfl_xor(s7, 8);
    s0 += __shfl_xor(s0, 16); s1 += __shfl_xor(s1, 16);
    s2 += __shfl_xor(s2, 16); s3 += __shfl_xor(s3, 16);
    s4 += __shfl_xor(s4, 16); s5 += __shfl_xor(s5, 16);
    s6 += __shfl_xor(s6, 16); s7 += __shfl_xor(s7, 16);
    s0 += __shfl_xor(s0, 32); s1 += __shfl_xor(s1, 32);
    s2 += __shfl_xor(s2, 32); s3 += __shfl_xor(s3, 32);
    s4 += __shfl_xor(s4, 32); s5 += __shfl_xor(s5, 32);
    s6 += __shfl_xor(s6, 32); s7 += __shfl_xor(s7, 32);

    if (l < 8) {
        uint4 pv = *(const uint4*)(hp + (long)node * FEAT2);   // self row
        s0 += __uint_as_float(pv.x << 16); s1 += __uint_as_float(pv.x & 0xffff0000u);
        s2 += __uint_as_float(pv.y << 16); s3 += __uint_as_float(pv.y & 0xffff0000u);
        s4 += __uint_as_float(pv.z << 16); s5 += __uint_as_float(pv.z & 0xffff0000u);
        s6 += __uint_as_float(pv.w << 16); s7 += __uint_as_float(pv.w & 0xffff0000u);
        float di = dinv[node];
        float4 ba = *(const float4*)(b1 + fofs + 8 * j);
        float4 bb4 = *(const float4*)(b1 + fofs + 8 * j + 4);
        float v0 = s0 * di + ba.x, v1 = s1 * di + ba.y;
        float v2 = s2 * di + ba.z, v3 = s3 * di + ba.w;
        float v4 = s4 * di + bb4.x, v5 = s5 * di + bb4.y;
        float v6 = s6 * di + bb4.z, v7 = s7 * di + bb4.w;
        v0 = v0 > 0.f ? v0 : 0.f; v1 = v1 > 0.f ? v1 : 0.f;
        v2 = v2 > 0.f ? v2 : 0.f; v3 = v3 > 0.f ? v3 : 0.f;
        v4 = v4 > 0.f ? v4 : 0.f; v5 = v5 > 0.f ? v5 : 0.f;
        v6 = v6 > 0.f ? v6 : 0.f; v7 = v7 > 0.f ? v7 : 0.f;
        uint4 o;
        o.x = (unsigned)f2bf(v0) | ((unsigned)f2bf(v1) << 16);
        o.y = (unsigned)f2bf(v2) | ((unsigned)f2bf(v3) << 16);
        o.z = (unsigned)f2bf(v4) | ((unsigned)f2bf(v5) << 16);
        o.w = (unsigned)f2bf(v6) | ((unsigned)f2bf(v7) << 16);
        *(uint4*)(a1 + (long)node * FEAT2 + fofs + 8 * j) = o;
    }
}

// ---- GEMM2 (MFMA): a1[M,128]bf16 x Bt2[48][128]bf16 -> h2s bf16, *dinv -----
__launch_bounds__(256)
__global__ void gemm2_mfma_kernel(const unsigned short* __restrict__ A,
                                  const unsigned short* __restrict__ Bt2,
                                  const float* __restrict__ dinv,
                                  unsigned short* __restrict__ C, int M) {
    int wave = blockIdx.x * (blockDim.x >> 6) + (threadIdx.x >> 6);
    int lane = threadIdx.x & 63;
    int quad = lane >> 4, r15 = lane & 15;
    int row0 = wave * 16;
    if (row0 >= M) return;
    int arow = row0 + r15;
    if (arow >= M) arow = M - 1;         // clamp: A row m only affects C row m

    bf16x8 af[4];
    const unsigned short* ap = A + (long)arow * FEAT2 + quad * 8;
    #pragma unroll
    for (int ks = 0; ks < 4; ks++) af[ks] = *(const bf16x8*)(ap + ks * 32);

    f32x4 acc[3];
    #pragma unroll
    for (int nt = 0; nt < 3; nt++) acc[nt] = (f32x4){0.f, 0.f, 0.f, 0.f};
    #pragma unroll
    for (int ks = 0; ks < 4; ks++) {
        #pragma unroll
        for (int nt = 0; nt < 3; nt++) {
            bf16x8 bf = *(const bf16x8*)(Bt2 + (long)(nt * 16 + r15) * FEAT2 + ks * 32 + quad * 8);
            acc[nt] = __builtin_amdgcn_mfma_f32_16x16x32_bf16(af[ks], bf, acc[nt], 0, 0, 0);
        }
    }

    // C/D: col=lane&15, row=quad*4+reg
    #pragma unroll
    for (int reg = 0; reg < 4; reg++) {
        int orow = row0 + quad * 4 + reg;
        if (orow >= M) continue;
        float di = dinv[orow];
        #pragma unroll
        for (int nt = 0; nt < 3; nt++) {
            int ocol = nt * 16 + r15;
            if (ocol < FEAT3)
                C[(long)orow * FEAT3 + ocol] = f2bf(acc[nt][reg] * di);
        }
    }
}

// ---- Aggregation 2 + log_softmax: quarter-wave uint2, full-chunk issue -----
__launch_bounds__(256)
__global__ void agg2_lsm_kernel(const unsigned short* __restrict__ h2s,
                                const int* __restrict__ col, const int* __restrict__ off,
                                const float* __restrict__ dinv, const float* __restrict__ b2,
                                float* __restrict__ out, int N) {
    int node = blockIdx.x * 4 + (threadIdx.x >> 6);
    if (node >= N) return;
    int l = threadIdx.x & 63;
    int q = l >> 4, jj = l & 15;
    bool act = jj < 10;
    const unsigned short* hp = h2s + 4 * jj;
    int o0 = off[node], o1 = off[node + 1];
    float s0 = 0.f, s1 = 0.f, s2 = 0.f, s3 = 0.f;

    #define ACC4(P)                                                     \
        do {                                                            \
            s0 += __uint_as_float((P).x << 16);                         \
            s1 += __uint_as_float((P).x & 0xffff0000u);                 \
            s2 += __uint_as_float((P).y << 16);                         \
            s3 += __uint_as_float((P).y & 0xffff0000u);                 \
        } while (0)

    for (int base = o0; base < o1; base += 64) {
        int cnt = min(64, o1 - base);
        int myc = (l < cnt) ? col[base + l] : 0;
        int quads = cnt >> 2;
        int i = 0;
        for (; i < quads; i += 8) {
            int lim = quads - i; if (lim > 8) lim = 8;
            uint2 P[8];
            #pragma unroll
            for (int u = 0; u < 8; u++) {
                if (u < lim) {
                    int c = __shfl(myc, 4 * (i + u) + q);
                    if (act) P[u] = *(const uint2*)(hp + (long)c * FEAT3);
                }
            }
            #pragma unroll
            for (int u = 0; u < 8; u++)
                if (u < lim && act) ACC4(P[u]);
        }
        int e = (quads << 2) + q;        // tail (e <= 63)
        int ct = __shfl(myc, e);
        if (e < cnt && act) {
            uint2 pt = *(const uint2*)(hp + (long)ct * FEAT3);
            ACC4(pt);
        }
    }
    #undef ACC4

    // combine the 4 edge slots (all lanes end with their jj's sums)
    s0 += __shfl_xor(s0, 16); s1 += __shfl_xor(s1, 16);
    s2 += __shfl_xor(s2, 16); s3 += __shfl_xor(s3, 16);
    s0 += __shfl_xor(s0, 32); s1 += __shfl_xor(s1, 32);
    s2 += __shfl_xor(s2, 32); s3 += __shfl_xor(s3, 32);

    float v0 = -INFINITY, v1 = -INFINITY, v2 = -INFINITY, v3 = -INFINITY;
    if (act) {
        uint2 pv = *(const uint2*)(hp + (long)node * FEAT3);   // self row
        s0 += __uint_as_float(pv.x << 16); s1 += __uint_as_float(pv.x & 0xffff0000u);
        s2 += __uint_as_float(pv.y << 16); s3 += __uint_as_float(pv.y & 0xffff0000u);
        float di = dinv[node];
        float4 b = *(const float4*)(b2 + 4 * jj);
        v0 = s0 * di + b.x; v1 = s1 * di + b.y;
        v2 = s2 * di + b.z; v3 = s3 * di + b.w;
    }
    float m = fmaxf(fmaxf(v0, v1), fmaxf(v2, v3));
    #pragma unroll
    for (int o = 1; o < 16; o <<= 1) m = fmaxf(m, __shfl_xor(m, o));
    float e = act ? (expf(v0 - m) + expf(v1 - m) + expf(v2 - m) + expf(v3 - m)) : 0.f;
    #pragma unroll
    for (int o = 1; o < 16; o <<= 1) e += __shfl_xor(e, o);
    float ls = logf(e);
    if (q == 0 && act) {
        *(float4*)(out + (long)node * FEAT3 + 4 * jj) =
            make_float4(v0 - m - ls, v1 - m - ls, v2 - m - ls, v3 - m - ls);
    }
}

// ---------------------------------------------------------------------------
extern "C" void kernel_launch(void* const* d_in, const int* in_sizes, int n_in,
                              void* d_out, int out_size, void* d_ws, size_t ws_size,
                              hipStream_t stream) {
    const float* x  = (const float*)d_in[0];
    const int*   ei = (const int*)d_in[1];
    const float* W1 = (const float*)d_in[2];
    const float* b1 = (const float*)d_in[3];
    const float* W2 = (const float*)d_in[4];
    const float* b2 = (const float*)d_in[5];
    float* out = (float*)d_out;

    const int  N = in_sizes[0] / FEAT1;       // 50000
    const long E = in_sizes[1] / 2;           // 1600000

    char* ws = (char*)d_ws;
    size_t off = 0;
    auto alloc = [&](size_t bytes) -> void* {
        off = (off + 255) & ~(size_t)255;
        void* p = ws + off;
        off += bytes;
        return p;
    };
    const int NB = (N + 255) >> 8;            // 196 buckets of 256 nodes
    const int bktCap = (int)(E / NB) + 1024;  // mean + >>10 sigma slack
    int*   offsets = (int*)alloc((size_t)(N + 1) * 4);
    float* dinv    = (float*)alloc((size_t)N * 4);
    int*   col     = (int*)alloc((size_t)E * 4);
    unsigned short* h1s = (unsigned short*)alloc((size_t)N * FEAT2 * 2);
    unsigned short* a1  = (unsigned short*)alloc((size_t)N * FEAT2 * 2);
    unsigned short* h2s = (unsigned short*)alloc((size_t)N * FEAT3 * 2);
    unsigned short* Bt  = (unsigned short*)alloc((size_t)FEAT2 * FEAT1 * 2);
    unsigned short* Bt2 = (unsigned short*)alloc((size_t)48 * FEAT2 * 2);
    unsigned* part = (unsigned*)alloc((size_t)NB * bktCap * 4);
    int*   gbkt    = (int*)alloc(256 * 4);

    // 7 dispatches: wbt (also zeroes gbkt), partA, partB, gemm1, agg1 (both
    // feature passes in one grid), gemm2, agg2.
    wbt_kernel<<<176, 256, 0, stream>>>(W1, W2, Bt, Bt2, gbkt);
    partA_kernel<<<256, 1024, 0, stream>>>(ei, gbkt, part, bktCap, E, NB);
    partB_kernel<<<NB, 512, 0, stream>>>(part, bktCap, gbkt, offsets, dinv, col, N, (int)E);
    {
        int tiles  = (N + 15) / 16;                        // 3125 row-tiles
        int blocks = (tiles + G1_NW * 2 - 1) / (G1_NW * 2); // 196
        gemm1_mfma_kernel<<<blocks, 512, 0, stream>>>(x, Bt, dinv, h1s, N);
    }
    {
        int nb = (N + 3) / 4;
        agg1_kernel<<<2 * nb, 256, 0, stream>>>(h1s, col, offsets, dinv, b1, a1, N, nb);
    }
    gemm2_mfma_kernel<<<(N / 16 + 3) / 4, 256, 0, stream>>>(a1, Bt2, dinv, h2s, N);
    agg2_lsm_kernel<<<(N + 3) / 4, 256, 0, stream>>>(h2s, col, offsets, dinv, b2, out, N);
}

// Round 8
// 302.771 us; speedup vs baseline: 1.0312x; 1.0312x over previous
//
#include <hip/hip_runtime.h>
#include <hip/hip_bf16.h>
#include <math.h>

// ---------------------------------------------------------------------------
// GCN 2-layer. A_hat = D^-1/2 (A+I) D^-1/2 factored: scale GEMM rows by dinv
// (epilogue), gather-sum neighbors, scale by dinv[dst], add self term.
// R8: CSR build, zero per-edge global atomics (two-level counting sort).
// R10: gemm1 whole-Bt-in-LDS + pre-swizzled B image. R11: 2 row-tiles/wave.
// R12-R14: gather kernels down the issue-depth gradient (quarter/octet-wave
// 16B gathers, feature-split two-pass agg1, unroll-4, partA single-read,
// partB 512t). -> 305.4us.
// R15 REGRESSED (+6.8): branchy P[8] full-chunk issue broke load batching
// (runtime `if (i<octs)` between loads -> conservative waitcnt at branch
// joins); merged agg1 dispatch mixed the two passes' L2 working sets.
// R16 (this): revert agg1/agg2 to R14-exact loop-bounded unroll-4
// (predicate-free loads; mean deg 32 = 4 octets, already fully covered);
// two agg1 dispatches restore the L2 split. One additive lever: partA
// 4-edge vector loads (int4 / 2xll2; chunk rounded to x4 for alignment,
// uniform-branch scalar fallback if E%4 != 0).
// Top-5 counters stay occluded by the harness 409.6MB re-poison (~60us).
// ---------------------------------------------------------------------------

#define FEAT1 512
#define FEAT2 128
#define FEAT3 40

typedef __attribute__((ext_vector_type(8))) short bf16x8;
typedef __attribute__((ext_vector_type(4))) float f32x4;

struct __align__(16) ll2 { long long x, y; };

__device__ __forceinline__ unsigned short f2bf(float f) {
    union { float f; unsigned u; } c; c.f = f;
    unsigned r = c.u + 0x7fff + ((c.u >> 16) & 1);   // round-nearest-even
    return (unsigned short)(r >> 16);
}
__device__ __forceinline__ float bf2f(unsigned v16) {
    union { unsigned u; float f; } c; c.u = v16 << 16;
    return c.f;
}

// f32x4 pair -> 8 bf16 via v_cvt_pk_bf16_f32 (compiler emits pk from casts)
__device__ __forceinline__ bf16x8 pack_bf8(f32x4 a, f32x4 b) {
    union { __hip_bfloat162 h[4]; bf16x8 v; } u;
    u.h[0] = __float22bfloat162_rn(make_float2(a[0], a[1]));
    u.h[1] = __float22bfloat162_rn(make_float2(a[2], a[3]));
    u.h[2] = __float22bfloat162_rn(make_float2(b[0], b[1]));
    u.h[3] = __float22bfloat162_rn(make_float2(b[2], b[3]));
    return u.v;
}

// ---- partA: bucket edges by dst>>8; LDS hist; 1 global claim/bucket/block --
// Single read of the edge list; 4 edges per thread per round via int4/ll2
// vector loads (chunk rounded to x4 so e0 is 16B-aligned; dst half aligned
// iff E%4==0 -- uniform fallback otherwise). Edges held in registers
// between the hist pass and the scatter pass.
__launch_bounds__(1024)
__global__ void partA_kernel(const int* __restrict__ ei,
                             int* __restrict__ gbkt, unsigned* __restrict__ part,
                             int bktCap, long E, int NB) {
    __shared__ int hist[256], lbase[256], lcur[256];
    __shared__ int anyv;
    int t = threadIdx.x;
    if (t == 0) anyv = 0;
    if (t < 256) { hist[t] = 0; lcur[t] = 0; }
    __syncthreads();
    if (t < 256 && ei[2 * t + 1] != 0) anyv = 1;   // benign race
    __syncthreads();
    int f64 = (anyv == 0) ? 1 : 0;
    const long long* ei64 = (const long long*)ei;
    bool al4 = ((E & 3) == 0);

    long chunk = (E + gridDim.x - 1) / gridDim.x;
    chunk = (chunk + 3) & ~3L;                      // x4 alignment of start
    long start = (long)blockIdx.x * chunk;
    long end = start + chunk; if (end > E) end = E;
    if (start > E) start = E;

    int srcs[8], dsts[8];
    #pragma unroll
    for (int r = 0; r < 2; r++) {
        long e0 = start + (long)r * 4096 + 4 * t;   // 16B-aligned
        if (al4 && e0 + 3 < end) {
            if (f64) {
                ll2 sa = *(const ll2*)(ei64 + e0);
                ll2 sb = *(const ll2*)(ei64 + e0 + 2);
                ll2 da = *(const ll2*)(ei64 + E + e0);
                ll2 db = *(const ll2*)(ei64 + E + e0 + 2);
                srcs[4 * r + 0] = (int)sa.x; srcs[4 * r + 1] = (int)sa.y;
                srcs[4 * r + 2] = (int)sb.x; srcs[4 * r + 3] = (int)sb.y;
                dsts[4 * r + 0] = (int)da.x; dsts[4 * r + 1] = (int)da.y;
                dsts[4 * r + 2] = (int)db.x; dsts[4 * r + 3] = (int)db.y;
            } else {
                int4 s4 = *(const int4*)(ei + e0);
                int4 d4 = *(const int4*)(ei + E + e0);
                srcs[4 * r + 0] = s4.x; srcs[4 * r + 1] = s4.y;
                srcs[4 * r + 2] = s4.z; srcs[4 * r + 3] = s4.w;
                dsts[4 * r + 0] = d4.x; dsts[4 * r + 1] = d4.y;
                dsts[4 * r + 2] = d4.z; dsts[4 * r + 3] = d4.w;
            }
            #pragma unroll
            for (int u = 0; u < 4; u++) atomicAdd(&hist[dsts[4 * r + u] >> 8], 1);
        } else {
            #pragma unroll
            for (int u = 0; u < 4; u++) {
                if (e0 + u < end) {
                    if (f64) { srcs[4 * r + u] = (int)ei64[e0 + u]; dsts[4 * r + u] = (int)ei64[E + e0 + u]; }
                    else     { srcs[4 * r + u] = ei[e0 + u];        dsts[4 * r + u] = ei[E + e0 + u]; }
                    atomicAdd(&hist[dsts[4 * r + u] >> 8], 1);
                }
            }
        }
    }
    __syncthreads();
    if (t < NB && hist[t]) lbase[t] = atomicAdd(&gbkt[t], hist[t]);
    __syncthreads();

    #pragma unroll
    for (int r = 0; r < 2; r++) {
        long e0 = start + (long)r * 4096 + 4 * t;
        #pragma unroll
        for (int u = 0; u < 4; u++) {
            if (e0 + u < end) {
                int bkt = dsts[4 * r + u] >> 8;
                int pos = lbase[bkt] + atomicAdd(&lcur[bkt], 1);
                if (pos < bktCap)
                    part[(long)bkt * bktCap + pos] =
                        (unsigned)srcs[4 * r + u] | ((unsigned)(dsts[4 * r + u] & 255) << 17);
            }
        }
    }
}

// ---- partB: bucket-base scan + per-bucket degree hist/scan -> offsets/dinv;
//      LDS-cursor scatter -> col. 512 threads (scans guarded to t<256). ----
__launch_bounds__(512)
__global__ void partB_kernel(const unsigned* __restrict__ part, int bktCap,
                             const int* __restrict__ gbkt,
                             int* __restrict__ offsets, float* __restrict__ dinv,
                             int* __restrict__ col, int N, int E) {
    __shared__ int h[256], sc[256], cur[256];
    int b = blockIdx.x, t = threadIdx.x;
    int NB = gridDim.x;

    // inclusive scan of gbkt (redundant per block) -> bucket base
    if (t < 256) sc[t] = (t < NB) ? gbkt[t] : 0;
    __syncthreads();
    #pragma unroll
    for (int d = 1; d < 256; d <<= 1) {
        int tv = 0;
        if (t < 256 && t >= d) tv = sc[t - d];
        __syncthreads();
        if (t < 256) sc[t] += tv;
        __syncthreads();
    }
    int base = (b == 0) ? 0 : sc[b - 1];
    if (b == 0 && t == 0) offsets[N] = E;

    int n = gbkt[b]; if (n > bktCap) n = bktCap;
    int lo = b << 8;
    const unsigned* p = part + (long)b * bktCap;
    if (t < 256) h[t] = 0;
    __syncthreads();
    for (int i = t; i < n; i += 512) atomicAdd(&h[(p[i] >> 17) & 255], 1);
    __syncthreads();
    int cnt = (t < 256) ? h[t] : 0;
    if (t < 256) sc[t] = cnt;
    __syncthreads();
    #pragma unroll
    for (int d = 1; d < 256; d <<= 1) {
        int tv = 0;
        if (t < 256 && t >= d) tv = sc[t - d];
        __syncthreads();
        if (t < 256) sc[t] += tv;
        __syncthreads();
    }
    if (t < 256) {
        int ex = sc[t] - cnt;
        int node = lo + t;
        if (node < N) {
            offsets[node] = base + ex;
            dinv[node] = 1.0f / sqrtf((float)(cnt + 1));   // +1 self-loop
        }
        cur[t] = ex;
    }
    __syncthreads();
    for (int i = t; i < n; i += 512) {
        unsigned u = p[i];
        int r = atomicAdd(&cur[(u >> 17) & 255], 1);
        col[base + r] = u & 0x1FFFF;
    }
}

// ---- merged weight prep: W1 -> Bt (pre-swizzled), W2 -> Bt2, zero gbkt -----
__global__ void wbt_kernel(const float* __restrict__ W1, const float* __restrict__ W2,
                           unsigned short* __restrict__ Bt, unsigned short* __restrict__ Bt2,
                           int* __restrict__ gbkt) {
    int b = blockIdx.x;                 // 0..175
    if (b == 0 && threadIdx.x < 256) gbkt[threadIdx.x] = 0;
    if (b < FEAT2) {
        int r = b, x7 = r & 7;
        for (int k = threadIdx.x; k < FEAT1; k += blockDim.x) {
            int c = k >> 3, j = k & 7;
            int eo = (((c ^ x7) << 3) | j);
            Bt[(long)r * FEAT1 + eo] = f2bf(W1[(long)k * FEAT2 + r]);
        }
    } else {
        int n = b - FEAT2;              // 0..47
        for (int k = threadIdx.x; k < FEAT2; k += blockDim.x)
            Bt2[(long)n * FEAT2 + k] = (n < FEAT3) ? f2bf(W2[(long)k * FEAT3 + n]) : 0;
    }
}

// ---- GEMM1 (MFMA): [M,512]f32 x Bt[128][512]bf16(swz) -> h1s bf16, *dinv ---
#define G1_NW 8   // waves per block (512 threads); 16 row-tiles per block
__launch_bounds__(512, 2)
__global__ void gemm1_mfma_kernel(const float* __restrict__ A,
                                  const unsigned short* __restrict__ Bsw,
                                  const float* __restrict__ dinv,
                                  unsigned short* __restrict__ C, int M) {
    __shared__ unsigned short Bl[FEAT2 * FEAT1];   // 128 KB swizzled B image
    int t = threadIdx.x;

    // stage: 512 threads x 16B x 16 rounds = 128 KB, linear copy
    {
        uint4 tmp[16];
        #pragma unroll
        for (int r = 0; r < 16; r++)
            tmp[r] = *(const uint4*)((const char*)Bsw + (size_t)t * 16 + (size_t)r * 8192);
        #pragma unroll
        for (int r = 0; r < 16; r++)
            *(uint4*)((char*)Bl + (size_t)t * 16 + (size_t)r * 8192) = tmp[r];
    }
    __syncthreads();

    int w = t >> 6, lane = t & 63;
    int quad = lane >> 4, r15 = lane & 15;
    int row0 = (blockIdx.x * (G1_NW * 2) + w * 2) * 16;   // first of 2 tiles
    int x7 = r15 & 7;

    int ar0 = row0 + r15;      if (ar0 >= M) ar0 = M - 1;  // clamp (see gemm2)
    int ar1 = row0 + 16 + r15; if (ar1 >= M) ar1 = M - 1;
    const float* ap0 = A + (long)ar0 * FEAT1 + quad * 8;
    const float* ap1 = A + (long)ar1 * FEAT1 + quad * 8;

    f32x4 ra0[3][2], ra1[3][2];          // depth-3 prefetch rings
    #pragma unroll
    for (int p = 0; p < 3; p++) {
        ra0[p][0] = *(const f32x4*)(ap0 + p * 32);
        ra0[p][1] = *(const f32x4*)(ap0 + p * 32 + 4);
        ra1[p][0] = *(const f32x4*)(ap1 + p * 32);
        ra1[p][1] = *(const f32x4*)(ap1 + p * 32 + 4);
    }

    f32x4 acc0[8], acc1[8];
    #pragma unroll
    for (int nt = 0; nt < 8; nt++) {
        acc0[nt] = (f32x4){0.f, 0.f, 0.f, 0.f};
        acc1[nt] = (f32x4){0.f, 0.f, 0.f, 0.f};
    }

    #pragma unroll
    for (int ks = 0; ks < 16; ks++) {
        int sl = ks % 3;
        bf16x8 af0 = pack_bf8(ra0[sl][0], ra0[sl][1]);
        bf16x8 af1 = pack_bf8(ra1[sl][0], ra1[sl][1]);
        if (ks < 13) {                   // refill freed slot (ks+3)
            ra0[sl][0] = *(const f32x4*)(ap0 + (ks + 3) * 32);
            ra0[sl][1] = *(const f32x4*)(ap0 + (ks + 3) * 32 + 4);
            ra1[sl][0] = *(const f32x4*)(ap1 + (ks + 3) * 32);
            ra1[sl][1] = *(const f32x4*)(ap1 + (ks + 3) * 32 + 4);
        }
        #pragma unroll
        for (int nt = 0; nt < 8; nt++) {
            // swizzled chunk: (ks*4 + quad) ^ (r15&7), 16B units
            int eo = (nt * 16 + r15) * FEAT1 + (((ks * 4 + quad) ^ x7) << 3);
            bf16x8 bfrag = *(const bf16x8*)(Bl + eo);
            acc0[nt] = __builtin_amdgcn_mfma_f32_16x16x32_bf16(af0, bfrag, acc0[nt], 0, 0, 0);
            acc1[nt] = __builtin_amdgcn_mfma_f32_16x16x32_bf16(af1, bfrag, acc1[nt], 0, 0, 0);
        }
    }

    // C/D: col=lane&15, row=quad*4+reg
    #pragma unroll
    for (int tile = 0; tile < 2; tile++) {
        #pragma unroll
        for (int reg = 0; reg < 4; reg++) {
            int orow = row0 + tile * 16 + quad * 4 + reg;
            if (orow < M) {
                float di = dinv[orow];
                #pragma unroll
                for (int nt = 0; nt < 8; nt++) {
                    float v = (tile == 0) ? acc0[nt][reg] : acc1[nt][reg];
                    C[(long)orow * FEAT2 + nt * 16 + r15] = f2bf(v * di);
                }
            }
        }
    }
}

// ---- Aggregation 1: feature-split octet gathers, unroll-4 ------------------
// Called twice (fofs = 0, 64). Lane l: q=l>>3 (edge slot, 8 edges/wave),
// j=l&7 covers feats fofs+8j..8j+7 (one dwordx4; 8 lanes x 16B = half row).
// Loop-bounded unroll-4 (predicate-free loads): 4 octets = 32 edges ~ one
// typical node in flight per wave.
__launch_bounds__(256)
__global__ void agg1_kernel(const unsigned short* __restrict__ h1s,
                            const int* __restrict__ col, const int* __restrict__ off,
                            const float* __restrict__ dinv, const float* __restrict__ b1,
                            unsigned short* __restrict__ a1, int N, int fofs) {
    int node = blockIdx.x * 4 + (threadIdx.x >> 6);
    if (node >= N) return;
    int l = threadIdx.x & 63;
    int q = l >> 3, j = l & 7;
    const unsigned short* hp = h1s + fofs + 8 * j;
    int o0 = off[node], o1 = off[node + 1];
    float s0 = 0.f, s1 = 0.f, s2 = 0.f, s3 = 0.f,
          s4 = 0.f, s5 = 0.f, s6 = 0.f, s7 = 0.f;

    #define ACC8(P)                                                     \
        do {                                                            \
            s0 += __uint_as_float((P).x << 16);                         \
            s1 += __uint_as_float((P).x & 0xffff0000u);                 \
            s2 += __uint_as_float((P).y << 16);                         \
            s3 += __uint_as_float((P).y & 0xffff0000u);                 \
            s4 += __uint_as_float((P).z << 16);                         \
            s5 += __uint_as_float((P).z & 0xffff0000u);                 \
            s6 += __uint_as_float((P).w << 16);                         \
            s7 += __uint_as_float((P).w & 0xffff0000u);                 \
        } while (0)

    for (int base = o0; base < o1; base += 64) {
        int cnt = min(64, o1 - base);
        int myc = (l < cnt) ? col[base + l] : 0;
        int octs = cnt >> 3;
        int i = 0;
        for (; i + 4 <= octs; i += 4) {
            int c0 = __shfl(myc, 8 * i + q);
            int c1 = __shfl(myc, 8 * i + 8 + q);
            int c2 = __shfl(myc, 8 * i + 16 + q);
            int c3 = __shfl(myc, 8 * i + 24 + q);
            uint4 p0 = *(const uint4*)(hp + (long)c0 * FEAT2);
            uint4 p1 = *(const uint4*)(hp + (long)c1 * FEAT2);
            uint4 p2 = *(const uint4*)(hp + (long)c2 * FEAT2);
            uint4 p3 = *(const uint4*)(hp + (long)c3 * FEAT2);
            ACC8(p0); ACC8(p1); ACC8(p2); ACC8(p3);
        }
        for (; i < octs; ++i) {
            int c0 = __shfl(myc, 8 * i + q);
            uint4 p0 = *(const uint4*)(hp + (long)c0 * FEAT2);
            ACC8(p0);
        }
        int e = (octs << 3) + q;         // tail: up to 7 edges (e <= 63)
        int ct = __shfl(myc, e);
        if (e < cnt) {
            uint4 p0 = *(const uint4*)(hp + (long)ct * FEAT2);
            ACC8(p0);
        }
    }
    #undef ACC8

    // combine the 8 edge slots
    s0 += __shfl_xor(s0, 8);  s1 += __shfl_xor(s1, 8);
    s2 += __shfl_xor(s2, 8);  s3 += __shfl_xor(s3, 8);
    s4 += __shfl_xor(s4, 8);  s5 += __shfl_xor(s5, 8);
    s6 += __shfl_xor(s6, 8);  s7 += __shfl_xor(s7, 8);
    s0 += __shfl_xor(s0, 16); s1 += __shfl_xor(s1, 16);
    s2 += __shfl_xor(s2, 16); s3 += __shfl_xor(s3, 16);
    s4 += __shfl_xor(s4, 16); s5 += __shfl_xor(s5, 16);
    s6 += __shfl_xor(s6, 16); s7 += __shfl_xor(s7, 16);
    s0 += __shfl_xor(s0, 32); s1 += __shfl_xor(s1, 32);
    s2 += __shfl_xor(s2, 32); s3 += __shfl_xor(s3, 32);
    s4 += __shfl_xor(s4, 32); s5 += __shfl_xor(s5, 32);
    s6 += __shfl_xor(s6, 32); s7 += __shfl_xor(s7, 32);

    if (l < 8) {
        uint4 pv = *(const uint4*)(hp + (long)node * FEAT2);   // self row
        s0 += __uint_as_float(pv.x << 16); s1 += __uint_as_float(pv.x & 0xffff0000u);
        s2 += __uint_as_float(pv.y << 16); s3 += __uint_as_float(pv.y & 0xffff0000u);
        s4 += __uint_as_float(pv.z << 16); s5 += __uint_as_float(pv.z & 0xffff0000u);
        s6 += __uint_as_float(pv.w << 16); s7 += __uint_as_float(pv.w & 0xffff0000u);
        float di = dinv[node];
        float4 ba = *(const float4*)(b1 + fofs + 8 * j);
        float4 bb = *(const float4*)(b1 + fofs + 8 * j + 4);
        float v0 = s0 * di + ba.x, v1 = s1 * di + ba.y;
        float v2 = s2 * di + ba.z, v3 = s3 * di + ba.w;
        float v4 = s4 * di + bb.x, v5 = s5 * di + bb.y;
        float v6 = s6 * di + bb.z, v7 = s7 * di + bb.w;
        v0 = v0 > 0.f ? v0 : 0.f; v1 = v1 > 0.f ? v1 : 0.f;
        v2 = v2 > 0.f ? v2 : 0.f; v3 = v3 > 0.f ? v3 : 0.f;
        v4 = v4 > 0.f ? v4 : 0.f; v5 = v5 > 0.f ? v5 : 0.f;
        v6 = v6 > 0.f ? v6 : 0.f; v7 = v7 > 0.f ? v7 : 0.f;
        uint4 o;
        o.x = (unsigned)f2bf(v0) | ((unsigned)f2bf(v1) << 16);
        o.y = (unsigned)f2bf(v2) | ((unsigned)f2bf(v3) << 16);
        o.z = (unsigned)f2bf(v4) | ((unsigned)f2bf(v5) << 16);
        o.w = (unsigned)f2bf(v6) | ((unsigned)f2bf(v7) << 16);
        *(uint4*)(a1 + (long)node * FEAT2 + fofs + 8 * j) = o;
    }
}

// ---- GEMM2 (MFMA): a1[M,128]bf16 x Bt2[48][128]bf16 -> h2s bf16, *dinv -----
__launch_bounds__(256)
__global__ void gemm2_mfma_kernel(const unsigned short* __restrict__ A,
                                  const unsigned short* __restrict__ Bt2,
                                  const float* __restrict__ dinv,
                                  unsigned short* __restrict__ C, int M) {
    int wave = blockIdx.x * (blockDim.x >> 6) + (threadIdx.x >> 6);
    int lane = threadIdx.x & 63;
    int quad = lane >> 4, r15 = lane & 15;
    int row0 = wave * 16;
    if (row0 >= M) return;
    int arow = row0 + r15;
    if (arow >= M) arow = M - 1;         // clamp: A row m only affects C row m

    bf16x8 af[4];
    const unsigned short* ap = A + (long)arow * FEAT2 + quad * 8;
    #pragma unroll
    for (int ks = 0; ks < 4; ks++) af[ks] = *(const bf16x8*)(ap + ks * 32);

    f32x4 acc[3];
    #pragma unroll
    for (int nt = 0; nt < 3; nt++) acc[nt] = (f32x4){0.f, 0.f, 0.f, 0.f};
    #pragma unroll
    for (int ks = 0; ks < 4; ks++) {
        #pragma unroll
        for (int nt = 0; nt < 3; nt++) {
            bf16x8 bf = *(const bf16x8*)(Bt2 + (long)(nt * 16 + r15) * FEAT2 + ks * 32 + quad * 8);
            acc[nt] = __builtin_amdgcn_mfma_f32_16x16x32_bf16(af[ks], bf, acc[nt], 0, 0, 0);
        }
    }

    // C/D: col=lane&15, row=quad*4+reg
    #pragma unroll
    for (int reg = 0; reg < 4; reg++) {
        int orow = row0 + quad * 4 + reg;
        if (orow >= M) continue;
        float di = dinv[orow];
        #pragma unroll
        for (int nt = 0; nt < 3; nt++) {
            int ocol = nt * 16 + r15;
            if (ocol < FEAT3)
                C[(long)orow * FEAT3 + ocol] = f2bf(acc[nt][reg] * di);
        }
    }
}

// ---- Aggregation 2 + log_softmax: quarter-wave uint2 gathers, unroll-4 -----
__launch_bounds__(256)
__global__ void agg2_lsm_kernel(const unsigned short* __restrict__ h2s,
                                const int* __restrict__ col, const int* __restrict__ off,
                                const float* __restrict__ dinv, const float* __restrict__ b2,
                                float* __restrict__ out, int N) {
    int node = blockIdx.x * 4 + (threadIdx.x >> 6);
    if (node >= N) return;
    int l = threadIdx.x & 63;
    int q = l >> 4, jj = l & 15;
    bool act = jj < 10;
    const unsigned short* hp = h2s + 4 * jj;
    int o0 = off[node], o1 = off[node + 1];
    float s0 = 0.f, s1 = 0.f, s2 = 0.f, s3 = 0.f;

    #define ACC4(P)                                                     \
        do {                                                            \
            s0 += __uint_as_float((P).x << 16);                         \
            s1 += __uint_as_float((P).x & 0xffff0000u);                 \
            s2 += __uint_as_float((P).y << 16);                         \
            s3 += __uint_as_float((P).y & 0xffff0000u);                 \
        } while (0)

    for (int base = o0; base < o1; base += 64) {
        int cnt = min(64, o1 - base);
        int myc = (l < cnt) ? col[base + l] : 0;
        int quads = cnt >> 2;
        int i = 0;
        for (; i + 4 <= quads; i += 4) {
            int c0 = __shfl(myc, 4 * i + q);
            int c1 = __shfl(myc, 4 * i + 4 + q);
            int c2 = __shfl(myc, 4 * i + 8 + q);
            int c3 = __shfl(myc, 4 * i + 12 + q);
            if (act) {
                uint2 p0 = *(const uint2*)(hp + (long)c0 * FEAT3);
                uint2 p1 = *(const uint2*)(hp + (long)c1 * FEAT3);
                uint2 p2 = *(const uint2*)(hp + (long)c2 * FEAT3);
                uint2 p3 = *(const uint2*)(hp + (long)c3 * FEAT3);
                ACC4(p0); ACC4(p1); ACC4(p2); ACC4(p3);
            }
        }
        for (; i < quads; ++i) {
            int c0 = __shfl(myc, 4 * i + q);
            if (act) {
                uint2 p0 = *(const uint2*)(hp + (long)c0 * FEAT3);
                ACC4(p0);
            }
        }
        int e = (quads << 2) + q;        // tail (e <= 63)
        int ct = __shfl(myc, e);
        if (e < cnt && act) {
            uint2 p0 = *(const uint2*)(hp + (long)ct * FEAT3);
            ACC4(p0);
        }
    }
    #undef ACC4

    // combine the 4 edge slots (all lanes end with their jj's sums)
    s0 += __shfl_xor(s0, 16); s1 += __shfl_xor(s1, 16);
    s2 += __shfl_xor(s2, 16); s3 += __shfl_xor(s3, 16);
    s0 += __shfl_xor(s0, 32); s1 += __shfl_xor(s1, 32);
    s2 += __shfl_xor(s2, 32); s3 += __shfl_xor(s3, 32);

    float v0 = -INFINITY, v1 = -INFINITY, v2 = -INFINITY, v3 = -INFINITY;
    if (act) {
        uint2 pv = *(const uint2*)(hp + (long)node * FEAT3);   // self row
        s0 += __uint_as_float(pv.x << 16); s1 += __uint_as_float(pv.x & 0xffff0000u);
        s2 += __uint_as_float(pv.y << 16); s3 += __uint_as_float(pv.y & 0xffff0000u);
        float di = dinv[node];
        float4 b = *(const float4*)(b2 + 4 * jj);
        v0 = s0 * di + b.x; v1 = s1 * di + b.y;
        v2 = s2 * di + b.z; v3 = s3 * di + b.w;
    }
    float m = fmaxf(fmaxf(v0, v1), fmaxf(v2, v3));
    #pragma unroll
    for (int o = 1; o < 16; o <<= 1) m = fmaxf(m, __shfl_xor(m, o));
    float e = act ? (expf(v0 - m) + expf(v1 - m) + expf(v2 - m) + expf(v3 - m)) : 0.f;
    #pragma unroll
    for (int o = 1; o < 16; o <<= 1) e += __shfl_xor(e, o);
    float ls = logf(e);
    if (q == 0 && act) {
        *(float4*)(out + (long)node * FEAT3 + 4 * jj) =
            make_float4(v0 - m - ls, v1 - m - ls, v2 - m - ls, v3 - m - ls);
    }
}

// ---------------------------------------------------------------------------
extern "C" void kernel_launch(void* const* d_in, const int* in_sizes, int n_in,
                              void* d_out, int out_size, void* d_ws, size_t ws_size,
                              hipStream_t stream) {
    const float* x  = (const float*)d_in[0];
    const int*   ei = (const int*)d_in[1];
    const float* W1 = (const float*)d_in[2];
    const float* b1 = (const float*)d_in[3];
    const float* W2 = (const float*)d_in[4];
    const float* b2 = (const float*)d_in[5];
    float* out = (float*)d_out;

    const int  N = in_sizes[0] / FEAT1;       // 50000
    const long E = in_sizes[1] / 2;           // 1600000

    char* ws = (char*)d_ws;
    size_t off = 0;
    auto alloc = [&](size_t bytes) -> void* {
        off = (off + 255) & ~(size_t)255;
        void* p = ws + off;
        off += bytes;
        return p;
    };
    const int NB = (N + 255) >> 8;            // 196 buckets of 256 nodes
    const int bktCap = (int)(E / NB) + 1024;  // mean + >>10 sigma slack
    int*   offsets = (int*)alloc((size_t)(N + 1) * 4);
    float* dinv    = (float*)alloc((size_t)N * 4);
    int*   col     = (int*)alloc((size_t)E * 4);
    unsigned short* h1s = (unsigned short*)alloc((size_t)N * FEAT2 * 2);
    unsigned short* a1  = (unsigned short*)alloc((size_t)N * FEAT2 * 2);
    unsigned short* h2s = (unsigned short*)alloc((size_t)N * FEAT3 * 2);
    unsigned short* Bt  = (unsigned short*)alloc((size_t)FEAT2 * FEAT1 * 2);
    unsigned short* Bt2 = (unsigned short*)alloc((size_t)48 * FEAT2 * 2);
    unsigned* part = (unsigned*)alloc((size_t)NB * bktCap * 4);
    int*   gbkt    = (int*)alloc(256 * 4);

    // 8 dispatches: wbt (also zeroes gbkt), partA (single-read x4 vector
    // loads), partB (512t, folds bucket scan), gemm1, agg1 x2 (feature-
    // split two-pass), gemm2, agg2.
    wbt_kernel<<<176, 256, 0, stream>>>(W1, W2, Bt, Bt2, gbkt);
    partA_kernel<<<256, 1024, 0, stream>>>(ei, gbkt, part, bktCap, E, NB);
    partB_kernel<<<NB, 512, 0, stream>>>(part, bktCap, gbkt, offsets, dinv, col, N, (int)E);
    {
        int tiles  = (N + 15) / 16;                        // 3125 row-tiles
        int blocks = (tiles + G1_NW * 2 - 1) / (G1_NW * 2); // 196
        gemm1_mfma_kernel<<<blocks, 512, 0, stream>>>(x, Bt, dinv, h1s, N);
    }
    agg1_kernel<<<(N + 3) / 4, 256, 0, stream>>>(h1s, col, offsets, dinv, b1, a1, N, 0);
    agg1_kernel<<<(N + 3) / 4, 256, 0, stream>>>(h1s, col, offsets, dinv, b1, a1, N, 64);
    gemm2_mfma_kernel<<<(N / 16 + 3) / 4, 256, 0, stream>>>(a1, Bt2, dinv, h2s, N);
    agg2_lsm_kernel<<<(N + 3) / 4, 256, 0, stream>>>(h2s, col, offsets, dinv, b2, out, N);
}